// Round 12
// baseline (43.689 us; speedup 1.0000x reference)
//
#include <hip/hip_runtime.h>
#include <hip/hip_fp16.h>
#include <math.h>

// Radon forward, exact reference semantics (rotated-lattice bilinear gather).
//
// Round-18 changes vs round 17 (40.0 us REGRESSION; champion r16 = 33.2 us):
//  * Post-mortem r17: wave-local dbuf+counted-vmcnt raised staged
//    cells/sample 2.67->4.0 and doubled per-event overhead -> T3/T4 does
//    not pay at this op's tiny compute phases. Reverted to r16 structure.
//  * NEW THEORY: r16's wall (~27 us main) is LDS bank conflicts. Staging
//    via global_load_lds forces row strides == 0 mod 32 banks -> bank =
//    V mod 32, row-independent. Lane map 16j x 4kk: kk groups at i-offsets
//    {0,3,6,9} have dV = 3 sin(theta) ~= 0 near 0 deg -> 4 kk groups hit
//    the SAME banks at DIFFERENT rows = 4-way conflict on every read
//    (2-way at 45 deg). ~2.5-3x on the dominant pipe == the wall; also
//    explains why all scheduling changes were neutral.
//  * FIX: per-row cell rotation (rule #21, swizzled-SOURCE staging):
//    cell (r,V) stored at LDS index r*32 + ((V + 8r) & 31). Rotation is
//    a multiple of the 4-cell granule -> 16B granules intact -> staging
//    keeps linear LDS dest, applies INVERSE rotation to per-lane global
//    source (gS = (gL - 2*ty) & 7). Staged bytes, instr count, occupancy
//    all unchanged. Banks: (V + 8r) mod 32 -> kk groups 24 banks apart at
//    theta=0 -> conflict-free; spread at all angles.
//  * Cost: x00/x01 LDS adjacency lost (wrap) -> gather = 4x ds_read_b32
//    + ~12 addr VALU/tap. Decisive A/B: win confirms conflicts were the
//    wall; regression -> revert r16, declare plateau.

#define G       363
#define NT      180
#define PADB    53
#define STEP    (2.0f / 362.0f)
#define DEG2RAD 0.017453292519943295f

#define TSW     32          // tile row length (u32 cells)
#define NJB     12          // j-blocks of 32
#define NJBF    6           // fallback j-blocks of 64
#define CW      264         // canvas cols (4 guard + 256 + 4 guard)
#define CH      264         // canvas rows

#define GLOAD16(gp, lp) __builtin_amdgcn_global_load_lds(                     \
    (const __attribute__((address_space(1))) void*)(gp),                      \
    (__attribute__((address_space(3))) void*)(lp), 16, 0, 0)

// ---------------- fallback gather kernel (known-good, round 1) -------------
__global__ __launch_bounds__(256) void radon_fwd(
    const float* __restrict__ x, const int* __restrict__ theta,
    float* __restrict__ out)
{
    const int t = blockIdx.x / NJBF, jb = blockIdx.x % NJBF;
    const int jl = threadIdx.x, chunk = threadIdx.y;
    const int j = jb * 64 + jl;
    const float th = (float)theta[t] * DEG2RAD;
    const float c = cosf(th), s = sinf(th);
    const float xj = fmaf((float)j, STEP, -1.0f);
    const float s181 = s * 181.0f, c181 = c * 181.0f;
    const float bx = fmaf(c, xj, 1.0f) * 181.0f;
    const float by = fmaf(-s, xj, 1.0f) * 181.0f;
    const float* img0 = x;
    const float* img1 = x + 65536;
    float acc0 = 0.f, acc1 = 0.f;
    for (int i = chunk; i < G; i += 4) {
        const float xi = fmaf((float)i, STEP, -1.0f);
        const float ix = fmaf(s181, xi, bx);
        const float iy = fmaf(c181, xi, by);
        const float fx = floorf(ix), fy = floorf(iy);
        const int ix0 = (int)fx, iy0 = (int)fy;
        const float wx1 = ix - fx, wy1 = iy - fy;
        const float wx0 = 1.f - wx1, wy0 = 1.f - wy1;
        const int cc0 = ix0 - 53, cc1 = cc0 + 1, rr0 = iy0 - 53, rr1 = rr0 + 1;
        const float wxa = ((unsigned)cc0 < 256u) ? wx0 : 0.f;
        const float wxb = ((unsigned)cc1 < 256u) ? wx1 : 0.f;
        const float wya = ((unsigned)rr0 < 256u) ? wy0 : 0.f;
        const float wyb = ((unsigned)rr1 < 256u) ? wy1 : 0.f;
        const int c0c = min(max(cc0, 0), 255), c1c = min(max(cc1, 0), 255);
        const int r0b = min(max(rr0, 0), 255) << 8, r1b = min(max(rr1, 0), 255) << 8;
        const float w00 = wya * wxa, w01 = wya * wxb, w10 = wyb * wxa, w11 = wyb * wxb;
        acc0 = fmaf(img0[r0b + c0c], w00, acc0);
        acc0 = fmaf(img0[r0b + c1c], w01, acc0);
        acc0 = fmaf(img0[r1b + c0c], w10, acc0);
        acc0 = fmaf(img0[r1b + c1c], w11, acc0);
        acc1 = fmaf(img1[r0b + c0c], w00, acc1);
        acc1 = fmaf(img1[r0b + c1c], w01, acc1);
        acc1 = fmaf(img1[r1b + c0c], w10, acc1);
        acc1 = fmaf(img1[r1b + c1c], w11, acc1);
    }
    __shared__ float red[2][4][64];
    red[0][chunk][jl] = acc0;
    red[1][chunk][jl] = acc1;
    __syncthreads();
    if (threadIdx.y < 2 && j < G) {
        const int n = threadIdx.y;
        out[n * (G * NT) + j * NT + t] =
            red[n][0][jl] + red[n][1][jl] + red[n][2][jl] + red[n][3][jl];
    }
}

// ------------- prep: f16x2 canvases only (guarded, normal + transposed) ----
__global__ __launch_bounds__(256) void prep_k(
    const float* __restrict__ x,
    unsigned* __restrict__ xIh, unsigned* __restrict__ xTIh)
{
    const int bid = blockIdx.x;            // 0..80 (9x9 grid of 32x32)
    const int tx = threadIdx.x, ty = threadIdx.y;

    __shared__ unsigned tl[32][33];
    const int cx0 = (bid % 9) * 32, cy0 = (bid / 9) * 32;
    #pragma unroll
    for (int dy = 0; dy < 32; dy += 8) {
        const int cy = cy0 + ty + dy, cx = cx0 + tx;
        const int pr = cy - 4, pc = cx - 4;
        unsigned v = 0u;
        if ((unsigned)pr < 256u && (unsigned)pc < 256u) {
            const int p = pr * 256 + pc;
            const unsigned short a = __half_as_ushort(__float2half_rn(x[p]));
            const unsigned short b = __half_as_ushort(__float2half_rn(x[p + 65536]));
            v = (unsigned)a | ((unsigned)b << 16);
        }
        if (cy < CH && cx < CW) xIh[cy * CW + cx] = v;
        tl[ty + dy][tx] = v;
    }
    __syncthreads();
    #pragma unroll
    for (int dy = 0; dy < 32; dy += 8) {
        const int rp = cx0 + ty + dy, cp = cy0 + tx;
        if (rp < CH && cp < CW) xTIh[rp * CW + cp] = tl[tx][ty + dy];
    }
}

// ------ staging: 4x global_load_lds, inverse-rotated per-lane source -------
// LDS layout: tile cell (ty, V) at index ty*32 + ((V + 8*ty) & 31).
// Granule view: LDS granule gL of row ty holds source granule (gL - 2*ty)&7
// (16B intact -> linear LDS dest + per-lane source, rule #21 compliant).
template<bool SAFE>
__device__ __forceinline__ void stage32(char* tileW_b,
    const unsigned* __restrict__ srcC, int r0p, int c0p, int lane)
{
    const int ty0 = lane >> 3;             // 0..7
    const int gL  = lane & 7;              // LDS granule within row
    #pragma unroll
    for (int u = 0; u < 4; ++u) {
        const int ty = ty0 + (u << 3);
        const int tx = ((gL - 2 * ty) & 7) << 2;   // inverse rotation
        int idx;
        if (SAFE) {
            idx = (r0p + 4 + ty) * CW + (c0p + 4 + tx);
        } else {
            // clamp into 4-wide zero guard: OOB taps read guaranteed zeros
            const int rc = min(max(r0p + ty, -4), 256) + 4;
            const int cc = min(max(c0p + tx, -4), 256) + 4;
            idx = rc * CW + cc;
        }
        GLOAD16(srcC + idx, tileW_b + (u << 10));
    }
}

// -------- gather inner loop (6 i-steps, rotated layout, 4x b32) ------------
template<bool TAIL>
__device__ __forceinline__ void gather6(const unsigned* __restrict__ tl,
    float Uf0, float Vf0, float dU, float dV, int iexc,
    float& a0, float& a1)
{
    __half2 acc = __float2half2_rn(0.0f);
    #pragma unroll
    for (int k = 0; k < 6; ++k) {
        const float Uf = fmaf((float)k, dU, Uf0);   // independent, no chain
        const float Vf = fmaf((float)k, dV, Vf0);
        const float fU = floorf(Uf), fV = floorf(Vf);
        const float wU1 = Uf - fU;
        const float wV1 = Vf - fV;
        const int r  = (int)fU;            // tile row,  0..30
        const int V  = (int)fV;            // tile col,  0..30
        const int r8 = r << 3;
        const int A  = r8 << 2;            // r*32
        const int B  = V + r8;             // V + 8r  (rotation key)
        const int i00 = A + (B & 31);
        const int i01 = A + ((B + 1) & 31);
        const int i10 = A + 32 + ((B + 8) & 31);
        const int i11 = A + 32 + ((B + 9) & 31);
        const __half2 x00 = *(const __half2*)(tl + i00);
        const __half2 x01 = *(const __half2*)(tl + i01);
        const __half2 x10 = *(const __half2*)(tl + i10);
        const __half2 x11 = *(const __half2*)(tl + i11);
        const __half2 wv2 = __float2half2_rn(wV1);
        const __half2 wu2 = __float2half2_rn(wU1);
        const __half2 t0 = __hfma2(wv2, __hsub2(x01, x00), x00);
        const __half2 t1 = __hfma2(wv2, __hsub2(x11, x10), x10);
        __half2 v = __hfma2(wu2, __hsub2(t1, t0), t0);
        if (TAIL && k >= iexc) v = __float2half2_rn(0.0f);   // phantom i >= G
        acc = __hadd2(acc, v);
    }
    a0 += __low2float(acc);
    a1 += __high2float(acc);
}

// ---------------- main gather: barrier-free wave-private tiles -------------
__global__ __launch_bounds__(256) void radon_wv3(
    const unsigned* __restrict__ xIh, const unsigned* __restrict__ xTIh,
    const int* __restrict__ theta, float* __restrict__ out)
{
    __shared__ unsigned tile[4 * TSW * TSW];   // 4 waves x 4 KB, private
    __shared__ float red[4][2][16];

    const int blk  = blockIdx.x;           // 0..2159
    const int t    = blk / NJB;
    const int jb   = blk - t * NJB;
    const int tid  = threadIdx.x;
    const int lane = tid & 63;
    const int wid  = tid >> 6;             // 0..3
    const int wj   = wid & 1;              // j half (16)
    const int wi   = wid >> 1;             // i half (192)
    const int jl   = lane & 15;            // j lane
    const int kk   = lane >> 4;            // i 6-group (0..3)

    unsigned* tileW = tile + wid * (TSW * TSW);
    char*     tileW_b = (char*)tileW;

    const float th = (float)theta[t] * DEG2RAD;
    const float c = cosf(th), s = sinf(th);
    const float s181 = s * 181.0f, c181 = c * 181.0f;

    const int caseA = (fabsf(c) >= fabsf(s));
    const unsigned* __restrict__ srcC = caseA ? xIh : xTIh;

    const float slopeU = caseA ? c181 : s181;
    const float slopeV = caseA ? s181 : c181;
    const float dU = slopeU * STEP;
    const float dV = slopeV * STEP;

    // per-lane sample base (U(i) = dU*i + U00L, padded-grid coords)
    const int   j  = jb * 32 + wj * 16 + jl;   // phantom j >= 363 ok
    const float xj = fmaf((float)j, STEP, -1.0f);
    const float bx = fmaf(c,  xj, 1.0f) * 181.0f;
    const float by = fmaf(-s, xj, 1.0f) * 181.0f;
    const float U00L = (caseA ? by : bx) - slopeU;
    const float V00L = (caseA ? bx : by) - slopeV;

    // wave-corner bases (identical fmaf chain, j endpoints of this wave)
    const int   j0  = jb * 32 + wj * 16;
    const float xjm = fmaf((float)j0,        STEP, -1.0f);
    const float xjM = fmaf((float)(j0 + 15), STEP, -1.0f);
    const float bxm = fmaf(c,  xjm, 1.0f) * 181.0f;
    const float bym = fmaf(-s, xjm, 1.0f) * 181.0f;
    const float bxM = fmaf(c,  xjM, 1.0f) * 181.0f;
    const float byM = fmaf(-s, xjM, 1.0f) * 181.0f;
    const float U00m = (caseA ? bym : bxm) - slopeU;
    const float U00M = (caseA ? byM : bxM) - slopeU;
    const float V00m = (caseA ? bxm : bym) - slopeV;
    const float V00M = (caseA ? bxM : byM) - slopeV;

    const float fiofs = (float)(kk * 6);

    float a0 = 0.f, a1 = 0.f;

    for (int sub = 0; sub < 8; ++sub) {
        const int i0 = (wi * 8 + sub) * 24;
        const float fi0 = (float)i0, fi1 = (float)(i0 + 23);

        // ---- bbox mins (4 corners each axis; same chain as samples) ----
        const float Umin = fminf(fminf(fmaf(dU, fi0, U00m), fmaf(dU, fi0, U00M)),
                                 fminf(fmaf(dU, fi1, U00m), fmaf(dU, fi1, U00M)));
        const float Vmin = fminf(fminf(fmaf(dV, fi0, V00m), fmaf(dV, fi0, V00M)),
                                 fminf(fmaf(dV, fi1, V00m), fmaf(dV, fi1, V00M)));
        const int r0 = __builtin_amdgcn_readfirstlane((int)floorf(Umin) - 1);
        const int c0 = __builtin_amdgcn_readfirstlane((int)floorf(Vmin) - 1);
        const int r0p = r0 - PADB, c0p = c0 - PADB;

        // ---- fence: prior subtile's ds_reads done before overwrite ----
        asm volatile("s_waitcnt lgkmcnt(0)" ::: "memory");
        __builtin_amdgcn_sched_barrier(0);

        if (r0p >= -4 && r0p <= 228 && c0p >= -4 && c0p <= 228)
            stage32<true >(tileW_b, srcC, r0p, c0p, lane);
        else
            stage32<false>(tileW_b, srcC, r0p, c0p, lane);

        // ---- wave-local drain; NO block barrier ----
        asm volatile("s_waitcnt vmcnt(0)" ::: "memory");
        __builtin_amdgcn_sched_barrier(0);

        // ---- gather 6 taps/lane, tile-relative coords ----
        const float fi  = fi0 + fiofs;
        const float Uf0 = fmaf(dU, fi, U00L) - (float)r0;
        const float Vf0 = fmaf(dV, fi, V00L) - (float)c0;
        const int ibase = i0 + kk * 6;

        if (i0 + 23 < G) {
            gather6<false>(tileW, Uf0, Vf0, dU, dV, 6, a0, a1);
        } else {
            gather6<true>(tileW, Uf0, Vf0, dU, dV, G - ibase, a0, a1);
        }
    }

    // ---- reduce kk groups in-wave, wi halves across waves ----
    a0 += __shfl_xor(a0, 16); a1 += __shfl_xor(a1, 16);
    a0 += __shfl_xor(a0, 32); a1 += __shfl_xor(a1, 32);

    if (lane < 16) {
        red[wid][0][lane] = a0;
        red[wid][1][lane] = a1;
    }
    __syncthreads();

    if (tid < 64) {
        const int n = tid >> 5, jj = tid & 31;
        const int wj2 = jj >> 4, jl2 = jj & 15;
        const float v = red[wj2][n][jl2] + red[wj2 + 2][n][jl2];
        const int jo = jb * 32 + jj;
        if (jo < G)
            out[(n * G + jo) * NT + t] = v;
    }
}

extern "C" void kernel_launch(void* const* d_in, const int* in_sizes, int n_in,
                              void* d_out, int out_size, void* d_ws, size_t ws_size,
                              hipStream_t stream) {
    const float* x     = (const float*)d_in[0];
    const int*   theta = (const int*)d_in[1];
    float*       out   = (float*)d_out;

    const size_t XIH_OFF  = 0;
    const size_t XTIH_OFF = (size_t)CH * CW * 4;                 // 278,784
    const size_t NEED     = 2 * XTIH_OFF;                        // 557,568 B

    if (ws_size < NEED) {   // fallback: known-good gather kernel
        hipLaunchKernelGGL(radon_fwd, dim3(NT * NJBF), dim3(64, 4), 0, stream,
                           x, theta, out);
        return;
    }

    unsigned* xIh  = (unsigned*)((char*)d_ws + XIH_OFF);
    unsigned* xTIh = (unsigned*)((char*)d_ws + XTIH_OFF);

    hipLaunchKernelGGL(prep_k, dim3(81), dim3(32, 8), 0, stream,
                       x, xIh, xTIh);
    hipLaunchKernelGGL(radon_wv3, dim3(NT * NJB), dim3(256), 0, stream,
                       xIh, xTIh, theta, out);
}

// Round 13
// 34.685 us; speedup vs baseline: 1.2596x; 1.2596x over previous
//
#include <hip/hip_runtime.h>
#include <hip/hip_fp16.h>
#include <math.h>

// Radon forward, exact reference semantics (rotated-lattice bilinear gather).
//
// Round-19 changes vs round 18 (43.7 us REGRESSION; champion r16 = 33.2 us):
//  * r18 counters (first main-kernel read since r11): VALUBusy 73%,
//    conflicts 3.94M cyc (~6 us), occupancy 45%. Rotation's ~12 VALU/tap
//    made it VALU-bound -> address arithmetic is the scarce currency.
//  * This round: r16 structure EXACTLY, but tile row stride 32 -> 36.
//    36 % 4 == 0 -> 16B staging granules stay row-pure (global_load_lds
//    legal); 36 % 32 != 0 -> bank = (4*row + V) mod 32. kk-groups
//    (delta-row = 6cos) land 24 banks apart at theta=0 -> worst 2-way
//    (free, m136) instead of r16's 4-way (1.58x). Gather changes ONLY the
//    fmaf literal (36.0f) -- zero added VALU.
//  * Staging: 9 granules/row (8 data + 1 pad, pad never read), 288
//    granules = 5 load iters (last half-masked), div-by-9 magic mul.
//    +12.5% staged bytes (pad) -- staging is ~5% of gather work.
//  * LDS: 4 waves x 36*32 cells = 18,432 B + red -> 8 blocks/CU, 32 waves.
//  * Everything else byte-identical to r16 (barrier-free wave-private
//    tiles, packed-f16 lerp, wave-local vmcnt fences).

#define G       363
#define NT      180
#define PADB    53
#define STEP    (2.0f / 362.0f)
#define DEG2RAD 0.017453292519943295f

#define TSW     36          // tile row STRIDE (u32 cells): %4==0, %32!=0
#define TCOL    32          // valid cols per row
#define GRPR    9           // granules per row (8 data + 1 pad)
#define NGRAN   (32 * GRPR) // 288 granules = 4608 cells = 18,432 B / wave
#define NJB     12          // j-blocks of 32
#define NJBF    6           // fallback j-blocks of 64
#define CW      264         // canvas cols (4 guard + 256 + 4 guard)
#define CH      264         // canvas rows

#define GLOAD16(gp, lp) __builtin_amdgcn_global_load_lds(                     \
    (const __attribute__((address_space(1))) void*)(gp),                      \
    (__attribute__((address_space(3))) void*)(lp), 16, 0, 0)

// ---------------- fallback gather kernel (known-good, round 1) -------------
__global__ __launch_bounds__(256) void radon_fwd(
    const float* __restrict__ x, const int* __restrict__ theta,
    float* __restrict__ out)
{
    const int t = blockIdx.x / NJBF, jb = blockIdx.x % NJBF;
    const int jl = threadIdx.x, chunk = threadIdx.y;
    const int j = jb * 64 + jl;
    const float th = (float)theta[t] * DEG2RAD;
    const float c = cosf(th), s = sinf(th);
    const float xj = fmaf((float)j, STEP, -1.0f);
    const float s181 = s * 181.0f, c181 = c * 181.0f;
    const float bx = fmaf(c, xj, 1.0f) * 181.0f;
    const float by = fmaf(-s, xj, 1.0f) * 181.0f;
    const float* img0 = x;
    const float* img1 = x + 65536;
    float acc0 = 0.f, acc1 = 0.f;
    for (int i = chunk; i < G; i += 4) {
        const float xi = fmaf((float)i, STEP, -1.0f);
        const float ix = fmaf(s181, xi, bx);
        const float iy = fmaf(c181, xi, by);
        const float fx = floorf(ix), fy = floorf(iy);
        const int ix0 = (int)fx, iy0 = (int)fy;
        const float wx1 = ix - fx, wy1 = iy - fy;
        const float wx0 = 1.f - wx1, wy0 = 1.f - wy1;
        const int cc0 = ix0 - 53, cc1 = cc0 + 1, rr0 = iy0 - 53, rr1 = rr0 + 1;
        const float wxa = ((unsigned)cc0 < 256u) ? wx0 : 0.f;
        const float wxb = ((unsigned)cc1 < 256u) ? wx1 : 0.f;
        const float wya = ((unsigned)rr0 < 256u) ? wy0 : 0.f;
        const float wyb = ((unsigned)rr1 < 256u) ? wy1 : 0.f;
        const int c0c = min(max(cc0, 0), 255), c1c = min(max(cc1, 0), 255);
        const int r0b = min(max(rr0, 0), 255) << 8, r1b = min(max(rr1, 0), 255) << 8;
        const float w00 = wya * wxa, w01 = wya * wxb, w10 = wyb * wxa, w11 = wyb * wxb;
        acc0 = fmaf(img0[r0b + c0c], w00, acc0);
        acc0 = fmaf(img0[r0b + c1c], w01, acc0);
        acc0 = fmaf(img0[r1b + c0c], w10, acc0);
        acc0 = fmaf(img0[r1b + c1c], w11, acc0);
        acc1 = fmaf(img1[r0b + c0c], w00, acc1);
        acc1 = fmaf(img1[r0b + c1c], w01, acc1);
        acc1 = fmaf(img1[r1b + c0c], w10, acc1);
        acc1 = fmaf(img1[r1b + c1c], w11, acc1);
    }
    __shared__ float red[2][4][64];
    red[0][chunk][jl] = acc0;
    red[1][chunk][jl] = acc1;
    __syncthreads();
    if (threadIdx.y < 2 && j < G) {
        const int n = threadIdx.y;
        out[n * (G * NT) + j * NT + t] =
            red[n][0][jl] + red[n][1][jl] + red[n][2][jl] + red[n][3][jl];
    }
}

// ------------- prep: f16x2 canvases only (guarded, normal + transposed) ----
__global__ __launch_bounds__(256) void prep_k(
    const float* __restrict__ x,
    unsigned* __restrict__ xIh, unsigned* __restrict__ xTIh)
{
    const int bid = blockIdx.x;            // 0..80 (9x9 grid of 32x32)
    const int tx = threadIdx.x, ty = threadIdx.y;

    __shared__ unsigned tl[32][33];
    const int cx0 = (bid % 9) * 32, cy0 = (bid / 9) * 32;
    #pragma unroll
    for (int dy = 0; dy < 32; dy += 8) {
        const int cy = cy0 + ty + dy, cx = cx0 + tx;
        const int pr = cy - 4, pc = cx - 4;
        unsigned v = 0u;
        if ((unsigned)pr < 256u && (unsigned)pc < 256u) {
            const int p = pr * 256 + pc;
            const unsigned short a = __half_as_ushort(__float2half_rn(x[p]));
            const unsigned short b = __half_as_ushort(__float2half_rn(x[p + 65536]));
            v = (unsigned)a | ((unsigned)b << 16);
        }
        if (cy < CH && cx < CW) xIh[cy * CW + cx] = v;
        tl[ty + dy][tx] = v;
    }
    __syncthreads();
    #pragma unroll
    for (int dy = 0; dy < 32; dy += 8) {
        const int rp = cx0 + ty + dy, cp = cy0 + tx;
        if (rp < CH && cp < CW) xTIh[rp * CW + cp] = tl[tx][ty + dy];
    }
}

// ------ staging: granule-indexed global_load_lds, row stride 36 ------------
// LDS cell (ty, tx) at index ty*36 + tx; granule g = ty*9 + gc holds cells
// tx in [gc*4, gc*4+4)  (gc == 8 is pad: staged but never read).
template<bool SAFE>
__device__ __forceinline__ void stage36(char* tileW_b,
    const unsigned* __restrict__ srcC, int r0p, int c0p, int lane)
{
    #pragma unroll
    for (int u = 0; u < 5; ++u) {
        const int g = lane + (u << 6);     // granule index
        if (u < 4 || g < NGRAN) {          // u<4 always; u=4: lanes 0..31
            const int ty = g / GRPR;       // magic-mul div by 9
            const int gc = g - ty * GRPR;
            const int tx = gc << 2;
            int idx;
            if (SAFE) {
                idx = (r0p + 4 + ty) * CW + (c0p + 4 + tx);
            } else {
                // clamp into 4-wide zero guard: OOB taps read zeros
                const int rc = min(max(r0p + ty, -4), 256) + 4;
                const int cc = min(max(c0p + tx, -4), 256) + 4;
                idx = rc * CW + cc;
            }
            GLOAD16(srcC + idx, tileW_b + (u << 10));
        }
    }
}

// -------- gather inner loop (6 i-steps, packed-f16 lerp, stride 36) --------
template<bool TAIL>
__device__ __forceinline__ void gather6(const unsigned* __restrict__ tl,
    float Uf0, float Vf0, float dU, float dV, int iexc,
    float& a0, float& a1)
{
    __half2 acc = __float2half2_rn(0.0f);
    #pragma unroll
    for (int k = 0; k < 6; ++k) {
        const float Uf = fmaf((float)k, dU, Uf0);   // independent, no chain
        const float Vf = fmaf((float)k, dV, Vf0);
        const float fU = floorf(Uf), fV = floorf(Vf);
        const float wU1 = Uf - fU;
        const float wV1 = Vf - fV;
        // fU*36+fV exact small ints; rel in [0, 1148)
        const int rel = (int)fmaf(fU, (float)TSW, fV);
        const __half2 x00 = *(const __half2*)(tl + rel);
        const __half2 x01 = *(const __half2*)(tl + rel + 1);
        const __half2 x10 = *(const __half2*)(tl + rel + TSW);
        const __half2 x11 = *(const __half2*)(tl + rel + TSW + 1);
        const __half2 wv2 = __float2half2_rn(wV1);
        const __half2 wu2 = __float2half2_rn(wU1);
        const __half2 t0 = __hfma2(wv2, __hsub2(x01, x00), x00);
        const __half2 t1 = __hfma2(wv2, __hsub2(x11, x10), x10);
        __half2 v = __hfma2(wu2, __hsub2(t1, t0), t0);
        if (TAIL && k >= iexc) v = __float2half2_rn(0.0f);   // phantom i >= G
        acc = __hadd2(acc, v);
    }
    a0 += __low2float(acc);
    a1 += __high2float(acc);
}

// ---------------- main gather: barrier-free wave-private tiles -------------
__global__ __launch_bounds__(256) void radon_wv4(
    const unsigned* __restrict__ xIh, const unsigned* __restrict__ xTIh,
    const int* __restrict__ theta, float* __restrict__ out)
{
    __shared__ unsigned tile[4 * NGRAN * 4];   // 4 waves x 18,432 B, private
    __shared__ float red[4][2][16];

    const int blk  = blockIdx.x;           // 0..2159
    const int t    = blk / NJB;
    const int jb   = blk - t * NJB;
    const int tid  = threadIdx.x;
    const int lane = tid & 63;
    const int wid  = tid >> 6;             // 0..3
    const int wj   = wid & 1;              // j half (16)
    const int wi   = wid >> 1;             // i half (192)
    const int jl   = lane & 15;            // j lane
    const int kk   = lane >> 4;            // i 6-group (0..3)

    unsigned* tileW = tile + wid * (NGRAN * 4);
    char*     tileW_b = (char*)tileW;

    const float th = (float)theta[t] * DEG2RAD;
    const float c = cosf(th), s = sinf(th);
    const float s181 = s * 181.0f, c181 = c * 181.0f;

    const int caseA = (fabsf(c) >= fabsf(s));
    const unsigned* __restrict__ srcC = caseA ? xIh : xTIh;

    const float slopeU = caseA ? c181 : s181;
    const float slopeV = caseA ? s181 : c181;
    const float dU = slopeU * STEP;
    const float dV = slopeV * STEP;

    // per-lane sample base (U(i) = dU*i + U00L, padded-grid coords)
    const int   j  = jb * 32 + wj * 16 + jl;   // phantom j >= 363 ok
    const float xj = fmaf((float)j, STEP, -1.0f);
    const float bx = fmaf(c,  xj, 1.0f) * 181.0f;
    const float by = fmaf(-s, xj, 1.0f) * 181.0f;
    const float U00L = (caseA ? by : bx) - slopeU;
    const float V00L = (caseA ? bx : by) - slopeV;

    // wave-corner bases (identical fmaf chain, j endpoints of this wave)
    const int   j0  = jb * 32 + wj * 16;
    const float xjm = fmaf((float)j0,        STEP, -1.0f);
    const float xjM = fmaf((float)(j0 + 15), STEP, -1.0f);
    const float bxm = fmaf(c,  xjm, 1.0f) * 181.0f;
    const float bym = fmaf(-s, xjm, 1.0f) * 181.0f;
    const float bxM = fmaf(c,  xjM, 1.0f) * 181.0f;
    const float byM = fmaf(-s, xjM, 1.0f) * 181.0f;
    const float U00m = (caseA ? bym : bxm) - slopeU;
    const float U00M = (caseA ? byM : bxM) - slopeU;
    const float V00m = (caseA ? bxm : bym) - slopeV;
    const float V00M = (caseA ? bxM : byM) - slopeV;

    const float fiofs = (float)(kk * 6);

    float a0 = 0.f, a1 = 0.f;

    for (int sub = 0; sub < 8; ++sub) {
        const int i0 = (wi * 8 + sub) * 24;
        const float fi0 = (float)i0, fi1 = (float)(i0 + 23);

        // ---- bbox mins (4 corners each axis; same chain as samples) ----
        const float Umin = fminf(fminf(fmaf(dU, fi0, U00m), fmaf(dU, fi0, U00M)),
                                 fminf(fmaf(dU, fi1, U00m), fmaf(dU, fi1, U00M)));
        const float Vmin = fminf(fminf(fmaf(dV, fi0, V00m), fmaf(dV, fi0, V00M)),
                                 fminf(fmaf(dV, fi1, V00m), fmaf(dV, fi1, V00M)));
        const int r0 = __builtin_amdgcn_readfirstlane((int)floorf(Umin) - 1);
        const int c0 = __builtin_amdgcn_readfirstlane((int)floorf(Vmin) - 1);
        const int r0p = r0 - PADB, c0p = c0 - PADB;

        // ---- fence: prior subtile's ds_reads done before overwrite ----
        asm volatile("s_waitcnt lgkmcnt(0)" ::: "memory");
        __builtin_amdgcn_sched_barrier(0);

        if (r0p >= -4 && r0p <= 228 && c0p >= -4 && c0p <= 224)
            stage36<true >(tileW_b, srcC, r0p, c0p, lane);
        else
            stage36<false>(tileW_b, srcC, r0p, c0p, lane);

        // ---- wave-local drain; NO block barrier ----
        asm volatile("s_waitcnt vmcnt(0)" ::: "memory");
        __builtin_amdgcn_sched_barrier(0);

        // ---- gather 6 taps/lane, tile-relative coords ----
        const float fi  = fi0 + fiofs;
        const float Uf0 = fmaf(dU, fi, U00L) - (float)r0;
        const float Vf0 = fmaf(dV, fi, V00L) - (float)c0;
        const int ibase = i0 + kk * 6;

        if (i0 + 23 < G) {
            gather6<false>(tileW, Uf0, Vf0, dU, dV, 6, a0, a1);
        } else {
            gather6<true>(tileW, Uf0, Vf0, dU, dV, G - ibase, a0, a1);
        }
    }

    // ---- reduce kk groups in-wave, wi halves across waves ----
    a0 += __shfl_xor(a0, 16); a1 += __shfl_xor(a1, 16);
    a0 += __shfl_xor(a0, 32); a1 += __shfl_xor(a1, 32);

    if (lane < 16) {
        red[wid][0][lane] = a0;
        red[wid][1][lane] = a1;
    }
    __syncthreads();

    if (tid < 64) {
        const int n = tid >> 5, jj = tid & 31;
        const int wj2 = jj >> 4, jl2 = jj & 15;
        const float v = red[wj2][n][jl2] + red[wj2 + 2][n][jl2];
        const int jo = jb * 32 + jj;
        if (jo < G)
            out[(n * G + jo) * NT + t] = v;
    }
}

extern "C" void kernel_launch(void* const* d_in, const int* in_sizes, int n_in,
                              void* d_out, int out_size, void* d_ws, size_t ws_size,
                              hipStream_t stream) {
    const float* x     = (const float*)d_in[0];
    const int*   theta = (const int*)d_in[1];
    float*       out   = (float*)d_out;

    const size_t XIH_OFF  = 0;
    const size_t XTIH_OFF = (size_t)CH * CW * 4;                 // 278,784
    const size_t NEED     = 2 * XTIH_OFF;                        // 557,568 B

    if (ws_size < NEED) {   // fallback: known-good gather kernel
        hipLaunchKernelGGL(radon_fwd, dim3(NT * NJBF), dim3(64, 4), 0, stream,
                           x, theta, out);
        return;
    }

    unsigned* xIh  = (unsigned*)((char*)d_ws + XIH_OFF);
    unsigned* xTIh = (unsigned*)((char*)d_ws + XTIH_OFF);

    hipLaunchKernelGGL(prep_k, dim3(81), dim3(32, 8), 0, stream,
                       x, xIh, xTIh);
    hipLaunchKernelGGL(radon_wv4, dim3(NT * NJB), dim3(256), 0, stream,
                       xIh, xTIh, theta, out);
}

// Round 14
// 32.054 us; speedup vs baseline: 1.3630x; 1.0821x over previous
//
#include <hip/hip_runtime.h>
#include <hip/hip_fp16.h>
#include <math.h>

// Radon forward, exact reference semantics (rotated-lattice bilinear gather).
//
// Round-20 changes vs round 19 (34.7 us; stride-36 conflict fix NET-NEGATIVE,
// reverted; champion r16 = 33.2 us):
//  * Conflict question closed (r18+r19): fixes cost more than the ~6 us they
//    can recover. Wall = VALU issue + per-subtile overhead.
//  * This round: r16 byte-identical EXCEPT the wave-uniform bbox work
//    (~180-200 VALU/wave = ~18-20% of the bound pipe, serialized between
//    fence and stage) moves to a prep-computed table:
//      - prep computes all 69,120 (t,jb,wj,wi,sub) subtile origins with the
//        IDENTICAL fmaf chain (bit-identical -> same +-1 margin proof).
//      - main prefetches its 8 origins as 4 static int4 loads at entry
//        (+16 VGPR, fully unrolled sub loop -> static indexing, no scratch).
//      - in-loop bbox cost: 2 readfirstlanes.
//  * Stride back to 32 (r19 revert). Everything else untouched r16.

#define G       363
#define NT      180
#define PADB    53
#define STEP    (2.0f / 362.0f)
#define DEG2RAD 0.017453292519943295f

#define TSW     32          // tile row length (u32 cells)
#define NJB     12          // j-blocks of 32
#define NJBF    6           // fallback j-blocks of 64
#define CW      264         // canvas cols (4 guard + 256 + 4 guard)
#define CH      264         // canvas rows
#define NWSLOT  (NT * NJB * 2 * 2)     // 8640 wave slots
#define NTUPLE  (NWSLOT * 8)           // 69120 subtile origins

#define GLOAD16(gp, lp) __builtin_amdgcn_global_load_lds(                     \
    (const __attribute__((address_space(1))) void*)(gp),                      \
    (__attribute__((address_space(3))) void*)(lp), 16, 0, 0)

// ---------------- fallback gather kernel (known-good, round 1) -------------
__global__ __launch_bounds__(256) void radon_fwd(
    const float* __restrict__ x, const int* __restrict__ theta,
    float* __restrict__ out)
{
    const int t = blockIdx.x / NJBF, jb = blockIdx.x % NJBF;
    const int jl = threadIdx.x, chunk = threadIdx.y;
    const int j = jb * 64 + jl;
    const float th = (float)theta[t] * DEG2RAD;
    const float c = cosf(th), s = sinf(th);
    const float xj = fmaf((float)j, STEP, -1.0f);
    const float s181 = s * 181.0f, c181 = c * 181.0f;
    const float bx = fmaf(c, xj, 1.0f) * 181.0f;
    const float by = fmaf(-s, xj, 1.0f) * 181.0f;
    const float* img0 = x;
    const float* img1 = x + 65536;
    float acc0 = 0.f, acc1 = 0.f;
    for (int i = chunk; i < G; i += 4) {
        const float xi = fmaf((float)i, STEP, -1.0f);
        const float ix = fmaf(s181, xi, bx);
        const float iy = fmaf(c181, xi, by);
        const float fx = floorf(ix), fy = floorf(iy);
        const int ix0 = (int)fx, iy0 = (int)fy;
        const float wx1 = ix - fx, wy1 = iy - fy;
        const float wx0 = 1.f - wx1, wy0 = 1.f - wy1;
        const int cc0 = ix0 - 53, cc1 = cc0 + 1, rr0 = iy0 - 53, rr1 = rr0 + 1;
        const float wxa = ((unsigned)cc0 < 256u) ? wx0 : 0.f;
        const float wxb = ((unsigned)cc1 < 256u) ? wx1 : 0.f;
        const float wya = ((unsigned)rr0 < 256u) ? wy0 : 0.f;
        const float wyb = ((unsigned)rr1 < 256u) ? wy1 : 0.f;
        const int c0c = min(max(cc0, 0), 255), c1c = min(max(cc1, 0), 255);
        const int r0b = min(max(rr0, 0), 255) << 8, r1b = min(max(rr1, 0), 255) << 8;
        const float w00 = wya * wxa, w01 = wya * wxb, w10 = wyb * wxa, w11 = wyb * wxb;
        acc0 = fmaf(img0[r0b + c0c], w00, acc0);
        acc0 = fmaf(img0[r0b + c1c], w01, acc0);
        acc0 = fmaf(img0[r1b + c0c], w10, acc0);
        acc0 = fmaf(img0[r1b + c1c], w11, acc0);
        acc1 = fmaf(img1[r0b + c0c], w00, acc1);
        acc1 = fmaf(img1[r0b + c1c], w01, acc1);
        acc1 = fmaf(img1[r1b + c0c], w10, acc1);
        acc1 = fmaf(img1[r1b + c1c], w11, acc1);
    }
    __shared__ float red[2][4][64];
    red[0][chunk][jl] = acc0;
    red[1][chunk][jl] = acc1;
    __syncthreads();
    if (threadIdx.y < 2 && j < G) {
        const int n = threadIdx.y;
        out[n * (G * NT) + j * NT + t] =
            red[n][0][jl] + red[n][1][jl] + red[n][2][jl] + red[n][3][jl];
    }
}

// --------- prep: f16x2 canvases + per-(wave,sub) bbox-origin table ---------
// Blocks [0,81): canvases.  [81,351): bbox table (one tuple per thread).
__global__ __launch_bounds__(256) void prep_k(
    const float* __restrict__ x, const int* __restrict__ theta,
    unsigned* __restrict__ xIh, unsigned* __restrict__ xTIh,
    int2* __restrict__ bbox)
{
    const int bid = blockIdx.x;
    const int tx = threadIdx.x, ty = threadIdx.y;
    const int tid = ty * 32 + tx;

    if (bid < 81) {
        __shared__ unsigned tl[32][33];
        const int cx0 = (bid % 9) * 32, cy0 = (bid / 9) * 32;
        #pragma unroll
        for (int dy = 0; dy < 32; dy += 8) {
            const int cy = cy0 + ty + dy, cx = cx0 + tx;
            const int pr = cy - 4, pc = cx - 4;
            unsigned v = 0u;
            if ((unsigned)pr < 256u && (unsigned)pc < 256u) {
                const int p = pr * 256 + pc;
                const unsigned short a = __half_as_ushort(__float2half_rn(x[p]));
                const unsigned short b = __half_as_ushort(__float2half_rn(x[p + 65536]));
                v = (unsigned)a | ((unsigned)b << 16);
            }
            if (cy < CH && cx < CW) xIh[cy * CW + cx] = v;
            tl[ty + dy][tx] = v;
        }
        __syncthreads();
        #pragma unroll
        for (int dy = 0; dy < 32; dy += 8) {
            const int rp = cx0 + ty + dy, cp = cy0 + tx;
            if (rp < CH && cp < CW) xTIh[rp * CW + cp] = tl[tx][ty + dy];
        }
    } else {
        const int tuple = (bid - 81) * 256 + tid;
        if (tuple < NTUPLE) {
            // decode: (((t*NJB + jb)*2 + wj)*2 + wi)*8 + sub
            const int sub = tuple & 7;
            const int ws  = tuple >> 3;
            const int wi  = ws & 1;
            const int wj  = (ws >> 1) & 1;
            const int jb  = (ws >> 2) % NJB;
            const int t   = (ws >> 2) / NJB;

            // ---- identical fmaf chain to the main kernel ----
            const float th = (float)theta[t] * DEG2RAD;
            const float c = cosf(th), s = sinf(th);
            const float s181 = s * 181.0f, c181 = c * 181.0f;
            const int caseA = (fabsf(c) >= fabsf(s));
            const float slopeU = caseA ? c181 : s181;
            const float slopeV = caseA ? s181 : c181;
            const float dU = slopeU * STEP;
            const float dV = slopeV * STEP;

            const int   j0  = jb * 32 + wj * 16;
            const float xjm = fmaf((float)j0,        STEP, -1.0f);
            const float xjM = fmaf((float)(j0 + 15), STEP, -1.0f);
            const float bxm = fmaf(c,  xjm, 1.0f) * 181.0f;
            const float bym = fmaf(-s, xjm, 1.0f) * 181.0f;
            const float bxM = fmaf(c,  xjM, 1.0f) * 181.0f;
            const float byM = fmaf(-s, xjM, 1.0f) * 181.0f;
            const float U00m = (caseA ? bym : bxm) - slopeU;
            const float U00M = (caseA ? byM : bxM) - slopeU;
            const float V00m = (caseA ? bxm : bym) - slopeV;
            const float V00M = (caseA ? bxM : byM) - slopeV;

            const int i0 = (wi * 8 + sub) * 24;
            const float fi0 = (float)i0, fi1 = (float)(i0 + 23);
            const float Umin = fminf(fminf(fmaf(dU, fi0, U00m), fmaf(dU, fi0, U00M)),
                                     fminf(fmaf(dU, fi1, U00m), fmaf(dU, fi1, U00M)));
            const float Vmin = fminf(fminf(fmaf(dV, fi0, V00m), fmaf(dV, fi0, V00M)),
                                     fminf(fmaf(dV, fi1, V00m), fmaf(dV, fi1, V00M)));
            const int r0 = (int)floorf(Umin) - 1;
            const int c0 = (int)floorf(Vmin) - 1;
            bbox[tuple] = make_int2(r0, c0);
        }
    }
}

// ---------------- staging: 4x global_load_lds into wave-private 32x32 ------
template<bool SAFE>
__device__ __forceinline__ void stage32(char* tileW_b,
    const unsigned* __restrict__ srcC, int r0p, int c0p, int lane)
{
    const int ty0 = lane >> 3;             // 0..7
    const int tx  = (lane & 7) << 2;       // 0,4,...,28 (4 cells/lane)
    #pragma unroll
    for (int u = 0; u < 4; ++u) {
        const int ty = ty0 + (u << 3);
        int idx;
        if (SAFE) {
            idx = (r0p + 4 + ty) * CW + (c0p + 4 + tx);
        } else {
            // clamp into 4-wide zero guard: OOB taps read guaranteed zeros
            const int rc = min(max(r0p + ty, -4), 256) + 4;
            const int cc = min(max(c0p + tx, -4), 256) + 4;
            idx = rc * CW + cc;
        }
        GLOAD16(srcC + idx, tileW_b + (u << 10));
    }
}

// ---------------- gather inner loop (6 i-steps, packed-f16 lerp) -----------
template<bool TAIL>
__device__ __forceinline__ void gather6(const unsigned* __restrict__ tl,
    float Uf0, float Vf0, float dU, float dV, int iexc,
    float& a0, float& a1)
{
    __half2 acc = __float2half2_rn(0.0f);
    #pragma unroll
    for (int k = 0; k < 6; ++k) {
        const float Uf = fmaf((float)k, dU, Uf0);   // independent, no chain
        const float Vf = fmaf((float)k, dV, Vf0);
        const float fU = floorf(Uf), fV = floorf(Vf);
        const float wU1 = Uf - fU;
        const float wV1 = Vf - fV;
        // fU*32+fV exact small ints; rel in [0, 1024)
        const int rel = (int)fmaf(fU, (float)TSW, fV);
        const __half2 x00 = *(const __half2*)(tl + rel);
        const __half2 x01 = *(const __half2*)(tl + rel + 1);
        const __half2 x10 = *(const __half2*)(tl + rel + TSW);
        const __half2 x11 = *(const __half2*)(tl + rel + TSW + 1);
        const __half2 wv2 = __float2half2_rn(wV1);
        const __half2 wu2 = __float2half2_rn(wU1);
        const __half2 t0 = __hfma2(wv2, __hsub2(x01, x00), x00);
        const __half2 t1 = __hfma2(wv2, __hsub2(x11, x10), x10);
        __half2 v = __hfma2(wu2, __hsub2(t1, t0), t0);
        if (TAIL && k >= iexc) v = __float2half2_rn(0.0f);   // phantom i >= G
        acc = __hadd2(acc, v);
    }
    a0 += __low2float(acc);
    a1 += __high2float(acc);
}

// ---------------- main gather: barrier-free wave-private tiles -------------
__global__ __launch_bounds__(256) void radon_wv5(
    const unsigned* __restrict__ xIh, const unsigned* __restrict__ xTIh,
    const int* __restrict__ theta, const int4* __restrict__ bbox4,
    float* __restrict__ out)
{
    __shared__ unsigned tile[4 * TSW * TSW];   // 4 waves x 4 KB, private
    __shared__ float red[4][2][16];

    const int blk  = blockIdx.x;           // 0..2159
    const int t    = blk / NJB;
    const int jb   = blk - t * NJB;
    const int tid  = threadIdx.x;
    const int lane = tid & 63;
    const int wid  = tid >> 6;             // 0..3
    const int wj   = wid & 1;              // j half (16)
    const int wi   = wid >> 1;             // i half (192)
    const int jl   = lane & 15;            // j lane
    const int kk   = lane >> 4;            // i 6-group (0..3)

    unsigned* tileW = tile + wid * (TSW * TSW);
    char*     tileW_b = (char*)tileW;

    // ---- prefetch this wave's 8 bbox origins (4 static int4 loads) ----
    const int ws = ((t * NJB + jb) * 2 + wj) * 2 + wi;   // wave slot
    const int4 bb0 = bbox4[ws * 4 + 0];    // {r0[0],c0[0],r0[1],c0[1]}
    const int4 bb1 = bbox4[ws * 4 + 1];
    const int4 bb2 = bbox4[ws * 4 + 2];
    const int4 bb3 = bbox4[ws * 4 + 3];

    const float th = (float)theta[t] * DEG2RAD;
    const float c = cosf(th), s = sinf(th);
    const float s181 = s * 181.0f, c181 = c * 181.0f;

    const int caseA = (fabsf(c) >= fabsf(s));
    const unsigned* __restrict__ srcC = caseA ? xIh : xTIh;

    const float slopeU = caseA ? c181 : s181;
    const float slopeV = caseA ? s181 : c181;
    const float dU = slopeU * STEP;
    const float dV = slopeV * STEP;

    // per-lane sample base (U(i) = dU*i + U00L, padded-grid coords)
    const int   j  = jb * 32 + wj * 16 + jl;   // phantom j >= 363 ok
    const float xj = fmaf((float)j, STEP, -1.0f);
    const float bx = fmaf(c,  xj, 1.0f) * 181.0f;
    const float by = fmaf(-s, xj, 1.0f) * 181.0f;
    const float U00L = (caseA ? by : bx) - slopeU;
    const float V00L = (caseA ? bx : by) - slopeV;

    const float fiofs = (float)(kk * 6);

    float a0 = 0.f, a1 = 0.f;

    #pragma unroll
    for (int sub = 0; sub < 8; ++sub) {
        // ---- static extraction of this subtile's origin ----
        int r0i, c0i;
        if      (sub == 0) { r0i = bb0.x; c0i = bb0.y; }
        else if (sub == 1) { r0i = bb0.z; c0i = bb0.w; }
        else if (sub == 2) { r0i = bb1.x; c0i = bb1.y; }
        else if (sub == 3) { r0i = bb1.z; c0i = bb1.w; }
        else if (sub == 4) { r0i = bb2.x; c0i = bb2.y; }
        else if (sub == 5) { r0i = bb2.z; c0i = bb2.w; }
        else if (sub == 6) { r0i = bb3.x; c0i = bb3.y; }
        else               { r0i = bb3.z; c0i = bb3.w; }
        const int r0 = __builtin_amdgcn_readfirstlane(r0i);
        const int c0 = __builtin_amdgcn_readfirstlane(c0i);
        const int r0p = r0 - PADB, c0p = c0 - PADB;

        // ---- fence: prior subtile's ds_reads done before overwrite ----
        asm volatile("s_waitcnt lgkmcnt(0)" ::: "memory");
        __builtin_amdgcn_sched_barrier(0);

        if (r0p >= -4 && r0p <= 228 && c0p >= -4 && c0p <= 228)
            stage32<true >(tileW_b, srcC, r0p, c0p, lane);
        else
            stage32<false>(tileW_b, srcC, r0p, c0p, lane);

        // ---- wave-local drain; NO block barrier ----
        asm volatile("s_waitcnt vmcnt(0)" ::: "memory");
        __builtin_amdgcn_sched_barrier(0);

        // ---- gather 6 taps/lane, tile-relative coords ----
        const int i0 = (wi * 8 + sub) * 24;
        const float fi  = (float)i0 + fiofs;
        const float Uf0 = fmaf(dU, fi, U00L) - (float)r0;
        const float Vf0 = fmaf(dV, fi, V00L) - (float)c0;
        const int ibase = i0 + kk * 6;

        if (i0 + 23 < G) {
            gather6<false>(tileW, Uf0, Vf0, dU, dV, 6, a0, a1);
        } else {
            gather6<true>(tileW, Uf0, Vf0, dU, dV, G - ibase, a0, a1);
        }
    }

    // ---- reduce kk groups in-wave, wi halves across waves ----
    a0 += __shfl_xor(a0, 16); a1 += __shfl_xor(a1, 16);
    a0 += __shfl_xor(a0, 32); a1 += __shfl_xor(a1, 32);

    if (lane < 16) {
        red[wid][0][lane] = a0;
        red[wid][1][lane] = a1;
    }
    __syncthreads();

    if (tid < 64) {
        const int n = tid >> 5, jj = tid & 31;
        const int wj2 = jj >> 4, jl2 = jj & 15;
        const float v = red[wj2][n][jl2] + red[wj2 + 2][n][jl2];
        const int jo = jb * 32 + jj;
        if (jo < G)
            out[(n * G + jo) * NT + t] = v;
    }
}

extern "C" void kernel_launch(void* const* d_in, const int* in_sizes, int n_in,
                              void* d_out, int out_size, void* d_ws, size_t ws_size,
                              hipStream_t stream) {
    const float* x     = (const float*)d_in[0];
    const int*   theta = (const int*)d_in[1];
    float*       out   = (float*)d_out;

    const size_t XIH_OFF  = 0;
    const size_t XTIH_OFF = (size_t)CH * CW * 4;                 // 278,784
    const size_t BBOX_OFF = 2 * XTIH_OFF;                        // 557,568
    const size_t NEED     = BBOX_OFF + (size_t)NTUPLE * 8;       // ~1.08 MB

    if (ws_size < NEED) {   // fallback: known-good gather kernel
        hipLaunchKernelGGL(radon_fwd, dim3(NT * NJBF), dim3(64, 4), 0, stream,
                           x, theta, out);
        return;
    }

    unsigned* xIh  = (unsigned*)((char*)d_ws + XIH_OFF);
    unsigned* xTIh = (unsigned*)((char*)d_ws + XTIH_OFF);
    int2*     bbox = (int2*)((char*)d_ws + BBOX_OFF);

    hipLaunchKernelGGL(prep_k, dim3(351), dim3(32, 8), 0, stream,
                       x, theta, xIh, xTIh, bbox);
    hipLaunchKernelGGL(radon_wv5, dim3(NT * NJB), dim3(256), 0, stream,
                       xIh, xTIh, theta, (const int4*)bbox, out);
}